// Round 15
// baseline (195.647 us; speedup 1.0000x reference)
//
#include <hip/hip_runtime.h>

#define N_PTS 150000
#define NK 27
#define CIN 128
#define COUT 128
#define BM 128
#define NBLK ((N_PTS + BM - 1) / BM)   // 1172

typedef __attribute__((ext_vector_type(8))) short bfrag8;   // 8 bf16
typedef __attribute__((ext_vector_type(4))) float facc4;    // 4 f32

__device__ inline unsigned short f2bf(float f) {
    unsigned u = __builtin_bit_cast(unsigned, f);
    u += 0x7FFFu + ((u >> 16) & 1u);            // RNE
    return (unsigned short)(u >> 16);
}
__device__ inline unsigned pack2(float a, float b) {
    return (unsigned)f2bf(a) | ((unsigned)f2bf(b) << 16);
}
__device__ inline void glds16(const void* g, void* l) {
    __builtin_amdgcn_global_load_lds(
        (const __attribute__((address_space(1))) void*)g,
        (__attribute__((address_space(3))) void*)l, 16, 0, 0);
}

// ---- prep: fp32 data -> bf16, plus one zeroed row at index N_PTS ----
__global__ void cast_data_kernel(const float* __restrict__ in,
                                 unsigned short* __restrict__ out) {
    const int n8_data = N_PTS * (CIN / 8);
    const int n8_all  = (N_PTS + 1) * (CIN / 8);
    int i = blockIdx.x * blockDim.x + threadIdx.x;
    int stride = gridDim.x * blockDim.x;
    for (; i < n8_all; i += stride) {
        uint4 v;
        if (i < n8_data) {
            const float4* p = (const float4*)(in + (size_t)i * 8);
            float4 x = p[0], y = p[1];
            v.x = pack2(x.x, x.y); v.y = pack2(x.z, x.w);
            v.z = pack2(y.x, y.y); v.w = pack2(y.z, y.w);
        } else {
            v.x = v.y = v.z = v.w = 0u;
        }
        *(uint4*)(out + (size_t)i * 8) = v;
    }
}

// ---- prep: W[co][k][ci] -> wkh[k][h2][co][bu] bf16 16B units, pre-swizzled bu^(co&7) ----
__global__ void prep_weights_h(const float* __restrict__ w,
                               unsigned short* __restrict__ wkh) {
    int i = blockIdx.x * blockDim.x + threadIdx.x;
    if (i >= NK * 2 * 128 * 8) return;
    int bu = i & 7, co = (i >> 3) & 127, h = (i >> 10) & 1, k = i >> 11;
    int ci = h * 64 + (bu ^ (co & 7)) * 8;
    const float4* src = (const float4*)(w + ((size_t)co * NK + k) * CIN + ci);
    float4 x = src[0], y = src[1];
    uint4 v;
    v.x = pack2(x.x, x.y); v.y = pack2(x.z, x.w);
    v.z = pack2(y.x, y.y); v.w = pack2(y.z, y.w);
    ((uint4*)wkh)[i] = v;
}

// ================= main kernel (v14: 64x64 waves — LDS bytes -25%) =================
// 256 threads / 4 waves, BM=128, wave = 64 rows x 64 couts (wrow 0..1, h 0..1).
// 54 phases (27 k x 2 ci-halves, K=64). Per block-phase LDS: 64 KB reads
// (B re-read factor 4 -> 2) + 32 KB writes. A/B double 2x16KB, idx slab 13.8KB
// -> 79,616 B -> 2 blocks/CU (independent blocks cover each other's drains).
// Per phase per thread: 4 B-glds + 4 A-glds; idx via LDS slab (lgkm domain).

#define STAGE_A(Q, ADST)                                                     \
  {                                                                          \
    const int k_  = (Q) >> 1;                                                \
    const int hb_ = ((Q) & 1) << 7;                                          \
    _Pragma("unroll")                                                        \
    for (int j_ = 0; j_ < 4; ++j_) {                                         \
      int iv = *(const int*)(ldsI + (sbase + j_ * 32) * 108 + k_ * 4);       \
      size_t e = (sok[j_] && iv >= 0) ? (size_t)iv : (size_t)N_PTS;          \
      glds16(dbfB + e * 256 + hb_ + aswz, (ADST) + j_ * 4096 + w * 1024);    \
    }                                                                        \
  }

#define STAGE_B(Q, BDST)                                                     \
  {                                                                          \
    const char* bs_ = wkhB + (size_t)(Q) * 16384 + w * 4096 + l * 16;        \
    _Pragma("unroll")                                                        \
    for (int j_ = 0; j_ < 4; ++j_)                                           \
      glds16(bs_ + j_ * 1024, (BDST) + w * 4096 + j_ * 1024);                \
  }

#define MFMA_PHASE(ABUF, BBUF)                                                      \
  {                                                                                 \
    __builtin_amdgcn_s_setprio(1);                                                  \
    _Pragma("unroll")                                                               \
    for (int kk = 0; kk < 2; ++kk) {                                                \
      const int sw_ = (((kk * 4 + lk) ^ (lr & 7)) << 4);                            \
      bfrag8 a0 = *(const bfrag8*)((ABUF) + (wrow * 64 + lr) * 128 + sw_);          \
      bfrag8 a1 = *(const bfrag8*)((ABUF) + (wrow * 64 + 16 + lr) * 128 + sw_);     \
      bfrag8 a2 = *(const bfrag8*)((ABUF) + (wrow * 64 + 32 + lr) * 128 + sw_);     \
      bfrag8 a3 = *(const bfrag8*)((ABUF) + (wrow * 64 + 48 + lr) * 128 + sw_);     \
      _Pragma("unroll")                                                             \
      for (int ct = 0; ct < 4; ++ct) {                                              \
        bfrag8 b = *(const bfrag8*)((BBUF) + (h * 64 + ct * 16 + lr) * 128 + sw_);  \
        acc[0][ct] = __builtin_amdgcn_mfma_f32_16x16x32_bf16(a0, b, acc[0][ct],     \
                                                             0, 0, 0);              \
        acc[1][ct] = __builtin_amdgcn_mfma_f32_16x16x32_bf16(a1, b, acc[1][ct],     \
                                                             0, 0, 0);              \
        acc[2][ct] = __builtin_amdgcn_mfma_f32_16x16x32_bf16(a2, b, acc[2][ct],     \
                                                             0, 0, 0);              \
        acc[3][ct] = __builtin_amdgcn_mfma_f32_16x16x32_bf16(a3, b, acc[3][ct],     \
                                                             0, 0, 0);              \
      }                                                                             \
    }                                                                               \
    __builtin_amdgcn_s_setprio(0);                                                  \
  }

#define WAIT_BAR(N)                                                          \
    __builtin_amdgcn_sched_barrier(0);                                       \
    asm volatile("s_waitcnt vmcnt(" #N ")" ::: "memory");                    \
    __builtin_amdgcn_s_barrier();                                            \
    __builtin_amdgcn_sched_barrier(0);

__global__ __launch_bounds__(256, 2)
void octconv_v14(const unsigned short* __restrict__ dbf,   // [N_PTS+1][128] bf16
                 const unsigned short* __restrict__ wkh,   // [27][2][128][8u] preswz
                 const int* __restrict__ nbr,
                 float* __restrict__ out) {
    // A 2x16K | B 2x16K | idx 13824 = 79616 B -> 2 blocks/CU
    __shared__ __align__(1024) unsigned char lds[4 * 16384 + 13824];

    const int t = threadIdx.x;
    const int w = t >> 6, l = t & 63;
    const int lr = l & 15, lk = l >> 4;
    const int h = w & 1, wrow = w >> 1;
    const int m0 = blockIdx.x * BM;

    // A staging: thread -> slots sbase + j*32 (j=0..3), unit lu = l&7
    const int lu   = l & 7;
    const int sbase = w * 8 + (l >> 3);                 // 0..31
    const int aswz  = (lu ^ (sbase & 7)) << 4;          // (sbase+32j)&7 == sbase&7
    bool sok[4];
#pragma unroll
    for (int j = 0; j < 4; ++j) sok[j] = (m0 + sbase + j * 32) < N_PTS;

    const char* dbfB = (const char*)dbf;
    const char* wkhB = (const char*)wkh;
    char* pA0 = (char*)lds;
    char* pA1 = (char*)lds + 16384;
    char* pB0 = (char*)lds + 32768;
    char* pB1 = (char*)lds + 49152;
    char* ldsI = (char*)lds + 65536;

    facc4 acc[4][4];
    const facc4 fz = {0.f, 0.f, 0.f, 0.f};
#pragma unroll
    for (int a = 0; a < 4; ++a)
#pragma unroll
        for (int b = 0; b < 4; ++b) acc[a][b] = fz;

    // ---- prologue 1: idx slab via glds (13824 B; guarded at tail block) ----
    {
        const char* nsrc = (const char*)nbr + (size_t)m0 * 108;
        const int rows_valid = (N_PTS - m0) < BM ? (N_PTS - m0) : BM;
        const int nlimit = rows_valid * 108;   // tail block: 112*108 = 12096 (16-aligned)
        int o;
        o = t * 16;         if (o < nlimit) glds16(nsrc + o, ldsI + o);
        o = 4096 + t * 16;  if (o < nlimit) glds16(nsrc + o, ldsI + o);
        o = 8192 + t * 16;  if (o < nlimit) glds16(nsrc + o, ldsI + o);
        o = 12288 + t * 16; if (t < 96 && o < nlimit) glds16(nsrc + o, ldsI + o);
    }
    WAIT_BAR(0)

    // ---- prologue 2: A(0), B(0) ----
    STAGE_A(0, pA0)
    STAGE_B(0, pB0)
    WAIT_BAR(0)

    // ---- phases 0..52: {B(p+1); A(p+1); MFMA(p); drain; swap} ----
#pragma unroll 1
    for (int p = 0; p <= 52; ++p) {
        STAGE_B(p + 1, pB1)
        STAGE_A(p + 1, pA1)
        MFMA_PHASE(pA0, pB0)
        WAIT_BAR(0)
        { char* tp = pA0; pA0 = pA1; pA1 = tp; }
        { char* tp = pB0; pB0 = pB1; pB1 = tp; }
    }

    // ---- phase 53: compute only ----
    MFMA_PHASE(pA0, pB0)

    // ---- epilogue: C/D col=lane&15, row=(lane>>4)*4+reg ----
#pragma unroll
    for (int rt = 0; rt < 4; ++rt) {
        const int r0 = m0 + wrow * 64 + rt * 16 + lk * 4;
#pragma unroll
        for (int ct = 0; ct < 4; ++ct) {
#pragma unroll
            for (int r = 0; r < 4; ++r) {
                int row = r0 + r;
                if (row < N_PTS)
                    out[(size_t)row * COUT + h * 64 + ct * 16 + lr] = acc[rt][ct][r];
            }
        }
    }
}

// ---- emergency fallback ----
__global__ void naive_kernel(const float* __restrict__ data, const float* __restrict__ wgt,
                             const int* __restrict__ nbr, float* __restrict__ out) {
    int mm = blockIdx.x;
    int co = threadIdx.x;
    if (mm >= N_PTS) return;
    float acc = 0.f;
    for (int k = 0; k < NK; ++k) {
        int idx = nbr[mm * NK + k];
        if (idx < 0) continue;
        const float* d  = data + (size_t)idx * CIN;
        const float* wp = wgt + ((size_t)co * NK + k) * CIN;
        for (int ci = 0; ci < CIN; ++ci) acc += d[ci] * wp[ci];
    }
    out[(size_t)mm * COUT + co] = acc;
}

extern "C" void kernel_launch(void* const* d_in, const int* in_sizes, int n_in,
                              void* d_out, int out_size, void* d_ws, size_t ws_size,
                              hipStream_t stream) {
    const float* data = (const float*)d_in[0];
    const float* wgt  = (const float*)d_in[1];
    const int*   nbr  = (const int*)d_in[2];
    float*       out  = (float*)d_out;

    const size_t wk_bytes  = (size_t)NK * 2 * 128 * 8 * 16;    // 884,736
    const size_t dbf_bytes = (size_t)(N_PTS + 1) * CIN * 2;    // 38,400,256

    if (ws_size < wk_bytes + dbf_bytes) {
        naive_kernel<<<N_PTS, COUT, 0, stream>>>(data, wgt, nbr, out);
        return;
    }
    unsigned short* wkh = (unsigned short*)d_ws;
    unsigned short* dbf = (unsigned short*)((char*)d_ws + wk_bytes);

    prep_weights_h<<<(NK * 2 * 128 * 8 + 255) / 256, 256, 0, stream>>>(wgt, wkh);
    cast_data_kernel<<<2048, 256, 0, stream>>>(data, dbf);

    octconv_v14<<<NBLK, 256, 0, stream>>>(dbf, wkh, nbr, out);
}

// Round 16
// 184.116 us; speedup vs baseline: 1.0626x; 1.0626x over previous
//
#include <hip/hip_runtime.h>

#define N_PTS 150000
#define NK 27
#define CIN 128
#define COUT 128
#define BM 128
#define NBLK ((N_PTS + BM - 1) / BM)   // 1172

typedef __attribute__((ext_vector_type(8))) short bfrag8;   // 8 bf16
typedef __attribute__((ext_vector_type(4))) float facc4;    // 4 f32

__device__ inline unsigned short f2bf(float f) {
    unsigned u = __builtin_bit_cast(unsigned, f);
    u += 0x7FFFu + ((u >> 16) & 1u);            // RNE
    return (unsigned short)(u >> 16);
}
__device__ inline unsigned pack2(float a, float b) {
    return (unsigned)f2bf(a) | ((unsigned)f2bf(b) << 16);
}
__device__ inline void glds16(const void* g, void* l) {
    __builtin_amdgcn_global_load_lds(
        (const __attribute__((address_space(1))) void*)g,
        (__attribute__((address_space(3))) void*)l, 16, 0, 0);
}

// ---- prep: fp32 data -> bf16, plus one zeroed row at index N_PTS ----
__global__ void cast_data_kernel(const float* __restrict__ in,
                                 unsigned short* __restrict__ out) {
    const int n8_data = N_PTS * (CIN / 8);
    const int n8_all  = (N_PTS + 1) * (CIN / 8);
    int i = blockIdx.x * blockDim.x + threadIdx.x;
    int stride = gridDim.x * blockDim.x;
    for (; i < n8_all; i += stride) {
        uint4 v;
        if (i < n8_data) {
            const float4* p = (const float4*)(in + (size_t)i * 8);
            float4 x = p[0], y = p[1];
            v.x = pack2(x.x, x.y); v.y = pack2(x.z, x.w);
            v.z = pack2(y.x, y.y); v.w = pack2(y.z, y.w);
        } else {
            v.x = v.y = v.z = v.w = 0u;
        }
        *(uint4*)(out + (size_t)i * 8) = v;
    }
}

// ---- prep: W[co][k][ci] -> wkh[k][h][co][bu] bf16 16B units, pre-swizzled bu^(co&7) ----
__global__ void prep_weights_h(const float* __restrict__ w,
                               unsigned short* __restrict__ wkh) {
    int i = blockIdx.x * blockDim.x + threadIdx.x;
    if (i >= NK * 2 * 128 * 8) return;
    int bu = i & 7, co = (i >> 3) & 127, h = (i >> 10) & 1, k = i >> 11;
    int ci = h * 64 + (bu ^ (co & 7)) * 8;
    const float4* src = (const float4*)(w + ((size_t)co * NK + k) * CIN + ci);
    float4 x = src[0], y = src[1];
    uint4 v;
    v.x = pack2(x.x, x.y); v.y = pack2(x.z, x.w);
    v.z = pack2(y.x, y.y); v.w = pack2(y.z, y.w);
    ((uint4*)wkh)[i] = v;
}

// ================= main kernel (v13 champion: triple-A + counted vmcnt(2)) =================
// 512 threads / 8 waves, BM=128, wave = 32 rows x 64 couts. 54 phases FULLY
// UNROLLED (compile-time phase ids -> static buffer names + static idx regs).
// A: glds gather, TRIPLE buffer 3x16KB, staged 2 phases ahead.
// B: glds, double buffer 2x16KB, staged 1 ahead. idx: VGPRs (iA/iB[27], loaded
// once in prologue; compiler manages residency/pipelining under full unroll).
// Steady queue after each barrier: [A(p+2) x2] -> WAIT_BAR(2).
// LDS = 3*16K + 2*16K = 81920 B exactly -> 2 blocks/CU (163840 = 160K).

#define STAGE_A(Q, ADST)                                                     \
  {                                                                          \
    const int hb_ = ((Q) & 1) << 7;                                          \
    int iv0 = iA[(Q) >> 1];                                                  \
    int iv1 = iB[(Q) >> 1];                                                  \
    size_t e0 = (s0ok && iv0 >= 0) ? (size_t)iv0 : (size_t)N_PTS;            \
    size_t e1 = (s1ok && iv1 >= 0) ? (size_t)iv1 : (size_t)N_PTS;            \
    glds16(dbfB + e0 * 256 + hb_ + aswz, (ADST) + s0 * 128 + lu16);          \
    glds16(dbfB + e1 * 256 + hb_ + aswz, (ADST) + s1 * 128 + lu16);          \
  }

#define STAGE_B(Q, BDST)                                                     \
  {                                                                          \
    const char* bs_ = wkhB + (size_t)(Q) * 16384 + t * 16;                   \
    glds16(bs_,        (BDST) + t * 16);                                     \
    glds16(bs_ + 8192, (BDST) + t * 16 + 8192);                              \
  }

#define MFMA_PHASE(ABUF, BBUF)                                                      \
  {                                                                                 \
    __builtin_amdgcn_s_setprio(1);                                                  \
    _Pragma("unroll")                                                               \
    for (int kk = 0; kk < 2; ++kk) {                                                \
      const int sw_ = (((kk * 4 + lk) ^ (lr & 7)) << 4);                            \
      bfrag8 a0 = *(const bfrag8*)((ABUF) + (wrow * 32 + lr) * 128 + sw_);          \
      bfrag8 a1 = *(const bfrag8*)((ABUF) + (wrow * 32 + 16 + lr) * 128 + sw_);     \
      _Pragma("unroll")                                                             \
      for (int ct = 0; ct < 4; ++ct) {                                              \
        bfrag8 b = *(const bfrag8*)((BBUF) + (h * 64 + ct * 16 + lr) * 128 + sw_);  \
        acc[0][ct] = __builtin_amdgcn_mfma_f32_16x16x32_bf16(a0, b, acc[0][ct],     \
                                                             0, 0, 0);              \
        acc[1][ct] = __builtin_amdgcn_mfma_f32_16x16x32_bf16(a1, b, acc[1][ct],     \
                                                             0, 0, 0);              \
      }                                                                             \
    }                                                                               \
    __builtin_amdgcn_s_setprio(0);                                                  \
  }

#define WAIT_BAR(N)                                                          \
    __builtin_amdgcn_sched_barrier(0);                                       \
    asm volatile("s_waitcnt vmcnt(" #N ")" ::: "memory");                    \
    __builtin_amdgcn_s_barrier();                                            \
    __builtin_amdgcn_sched_barrier(0);

// standard phase: {stage B(Q+1)->BW; stage A(Q+2)->AW; MFMA from AR,BR; wait 2}
#define PH_STD(Q, AR, AW, BR, BW)                                            \
    STAGE_B((Q) + 1, BW)                                                     \
    STAGE_A((Q) + 2, AW)                                                     \
    MFMA_PHASE(AR, BR)                                                       \
    WAIT_BAR(2)

// 6 phases = full buffer rotation period (A%3 x B%2), P must be %6==0
#define GROUP6(P)                                                            \
    PH_STD((P) + 0, pA0, pA2, pB0, pB1)                                      \
    PH_STD((P) + 1, pA1, pA0, pB1, pB0)                                      \
    PH_STD((P) + 2, pA2, pA1, pB0, pB1)                                      \
    PH_STD((P) + 3, pA0, pA2, pB1, pB0)                                      \
    PH_STD((P) + 4, pA1, pA0, pB0, pB1)                                      \
    PH_STD((P) + 5, pA2, pA1, pB1, pB0)

__global__ __launch_bounds__(512, 4)
void octconv_v13(const unsigned short* __restrict__ dbf,   // [N_PTS+1][128] bf16
                 const unsigned short* __restrict__ wkh,   // [27][2][128][8u] preswz
                 const int* __restrict__ nbr,
                 float* __restrict__ out) {
    // A triple 48K | B double 32K = 81920 B exactly -> 2 blocks/CU
    __shared__ __align__(1024) unsigned char lds[3 * 16384 + 2 * 16384];

    const int t = threadIdx.x;
    const int w = t >> 6, l = t & 63;
    const int lr = l & 15, lk = l >> 4;
    const int h = w & 1, wrow = w >> 1;
    const int m0 = blockIdx.x * BM;

    // A staging: thread -> slots s0=(t>>3), s0+64; units l&7 (lane-linear dest)
    const int lu   = l & 7;
    const int lu16 = lu * 16;
    const int s0 = t >> 3;
    const int s1 = s0 + 64;
    const bool s0ok = (m0 + s0) < N_PTS;
    const bool s1ok = (m0 + s1) < N_PTS;
    const int aswz = (lu ^ (s0 & 7)) << 4;    // s1&7 == s0&7

    const char* dbfB = (const char*)dbf;
    const char* wkhB = (const char*)wkh;
    char* pA0 = (char*)lds;                   // static buffer names (no rotation)
    char* pA1 = (char*)lds + 16384;
    char* pA2 = (char*)lds + 32768;
    char* pB0 = (char*)lds + 49152;
    char* pB1 = (char*)lds + 65536;

    facc4 acc[2][4];
    const facc4 fz = {0.f, 0.f, 0.f, 0.f};
#pragma unroll
    for (int a = 0; a < 2; ++a)
#pragma unroll
        for (int b = 0; b < 4; ++b) acc[a][b] = fz;

    // ---- prologue 1: idx -> VGPRs (one-time; outside loop vmcnt domain) ----
    int iA[27], iB[27];
    {
        const int r0 = (m0 + s0) < N_PTS ? (m0 + s0) : (N_PTS - 1);
        const int r1 = (m0 + s1) < N_PTS ? (m0 + s1) : (N_PTS - 1);
        const int* p0 = nbr + (size_t)r0 * NK;
        const int* p1 = nbr + (size_t)r1 * NK;
#pragma unroll
        for (int j = 0; j < 27; ++j) iA[j] = p0[j];
#pragma unroll
        for (int j = 0; j < 27; ++j) iB[j] = p1[j];
    }

    // ---- prologue 2: A(0),B(0),A(1) -> wait leaves A(1)x2 in flight ----
    STAGE_A(0, pA0)
    STAGE_B(0, pB0)
    STAGE_A(1, pA1)
    WAIT_BAR(2)

    // ---- phases 0..47: 8 full rotation groups ----
    GROUP6(0)  GROUP6(6)  GROUP6(12) GROUP6(18)
    GROUP6(24) GROUP6(30) GROUP6(36) GROUP6(42)

    // ---- phases 48..51 (uniform) ----
    PH_STD(48, pA0, pA2, pB0, pB1)
    PH_STD(49, pA1, pA0, pB1, pB0)
    PH_STD(50, pA2, pA1, pB0, pB1)
    PH_STD(51, pA0, pA2, pB1, pB0)   // stages A(53)->pA2, B(52)->pB0

    // ---- phase 52: stage B(53)->pB1; compute; drain all ----
    STAGE_B(53, pB1)
    MFMA_PHASE(pA1, pB0)
    WAIT_BAR(0)

    // ---- phase 53: compute only ----
    MFMA_PHASE(pA2, pB1)

    // ---- epilogue: C/D col=lane&15, row=(lane>>4)*4+reg ----
#pragma unroll
    for (int rt = 0; rt < 2; ++rt) {
        const int r0 = m0 + wrow * 32 + rt * 16 + lk * 4;
#pragma unroll
        for (int ct = 0; ct < 4; ++ct) {
#pragma unroll
            for (int r = 0; r < 4; ++r) {
                int row = r0 + r;
                if (row < N_PTS)
                    out[(size_t)row * COUT + h * 64 + ct * 16 + lr] = acc[rt][ct][r];
            }
        }
    }
}

// ---- emergency fallback ----
__global__ void naive_kernel(const float* __restrict__ data, const float* __restrict__ wgt,
                             const int* __restrict__ nbr, float* __restrict__ out) {
    int mm = blockIdx.x;
    int co = threadIdx.x;
    if (mm >= N_PTS) return;
    float acc = 0.f;
    for (int k = 0; k < NK; ++k) {
        int idx = nbr[mm * NK + k];
        if (idx < 0) continue;
        const float* d  = data + (size_t)idx * CIN;
        const float* wp = wgt + ((size_t)co * NK + k) * CIN;
        for (int ci = 0; ci < CIN; ++ci) acc += d[ci] * wp[ci];
    }
    out[(size_t)mm * COUT + co] = acc;
}

extern "C" void kernel_launch(void* const* d_in, const int* in_sizes, int n_in,
                              void* d_out, int out_size, void* d_ws, size_t ws_size,
                              hipStream_t stream) {
    const float* data = (const float*)d_in[0];
    const float* wgt  = (const float*)d_in[1];
    const int*   nbr  = (const int*)d_in[2];
    float*       out  = (float*)d_out;

    const size_t wk_bytes  = (size_t)NK * 2 * 128 * 8 * 16;    // 884,736
    const size_t dbf_bytes = (size_t)(N_PTS + 1) * CIN * 2;    // 38,400,256

    if (ws_size < wk_bytes + dbf_bytes) {
        naive_kernel<<<N_PTS, COUT, 0, stream>>>(data, wgt, nbr, out);
        return;
    }
    unsigned short* wkh = (unsigned short*)d_ws;
    unsigned short* dbf = (unsigned short*)((char*)d_ws + wk_bytes);

    prep_weights_h<<<(NK * 2 * 128 * 8 + 255) / 256, 256, 0, stream>>>(wgt, wkh);
    cast_data_kernel<<<2048, 256, 0, stream>>>(data, dbf);

    octconv_v13<<<NBLK, 512, 0, stream>>>(dbf, wkh, nbr, out);
}